// Round 7
// baseline (624.475 us; speedup 1.0000x reference)
//
#include <hip/hip_runtime.h>
#include <hip/hip_bf16.h>
#include <math.h>

typedef __attribute__((ext_vector_type(8))) short short8;
typedef __attribute__((ext_vector_type(4))) float f32x4;

#define KN 100
#define NBP 8   // batch elements per block

// ---- ws layout (halfword units) ----
#define W1_OFF 0         // 64x128 bf16, B-frag swizzled, kt=4
#define W2_OFF 8192      // 64x64, kt=2
#define W3_OFF 12288     // 32x64, kt=2
#define W4_OFF 14336     // 32x32, kt=1
#define SCRU_OFF 16384                        // 100000 x 128 bf16 (zero-padded j>=100)
#define SCRI_OFF (SCRU_OFF + 100000 * 128)    // 50000 x 128
#define EMBU_OFF (SCRI_OFF + 50000 * 128)     // 100000 x 64 bf16
#define EMBI_OFF (EMBU_OFF + 100000 * 64)     // 50000 x 64

// ---- LDS layout (halfword offsets) ----
#define ETB0 0            // 64 x 136 (user E^T)
#define ETB1 8704         // 64 x 136 (item E^T)
#define XU   17408        // 112 x 72
#define XI   25472        // 112 x 72
#define S_TOT 33536       // 67072 B

__device__ __forceinline__ unsigned short f2bf(float f) {
  __hip_bfloat16 h = __float2bfloat16(f);
  return __builtin_bit_cast(unsigned short, h);
}

__device__ __forceinline__ void st8(unsigned short* d, float4 a, float4 b) {
  short8 h;
  h[0] = (short)f2bf(a.x); h[1] = (short)f2bf(a.y);
  h[2] = (short)f2bf(a.z); h[3] = (short)f2bf(a.w);
  h[4] = (short)f2bf(b.x); h[5] = (short)f2bf(b.y);
  h[6] = (short)f2bf(b.z); h[7] = (short)f2bf(b.w);
  *reinterpret_cast<short8*>(d) = h;
}

// Streaming prep: weights (B-frag swizzle) + scr (bf16, pad to 128) + emb (bf16).
__global__ void prep(const float* __restrict__ w1, const float* __restrict__ w2,
                     const float* __restrict__ w3, const float* __restrict__ w4,
                     const float* __restrict__ uscr, const float* __restrict__ iscr,
                     const float* __restrict__ uemb, const float* __restrict__ iemb,
                     unsigned short* __restrict__ ws) {
  int t = blockIdx.x * 256 + threadIdx.x;
  if (t < 15360) {
    const float* src; int rel, o, i, kt, base;
    if (t < 8192)       { src = w1; rel = t;         o = rel >> 7; i = rel & 127; kt = 4; base = W1_OFF; }
    else if (t < 12288) { src = w2; rel = t - 8192;  o = rel >> 6; i = rel & 63;  kt = 2; base = W2_OFF; }
    else if (t < 14336) { src = w3; rel = t - 12288; o = rel >> 6; i = rel & 63;  kt = 2; base = W3_OFF; }
    else                { src = w4; rel = t - 14336; o = rel >> 5; i = rel & 31;  kt = 1; base = W4_OFF; }
    int n = o >> 4, l15 = o & 15, k = i >> 5, quad = (i >> 3) & 3, j = i & 7;
    ws[base + ((n * kt + k) * 64 + quad * 16 + l15) * 8 + j] = f2bf(src[rel]);
    return;
  }
  int rel = t - 15360;
  const float4 z4 = {0.f, 0.f, 0.f, 0.f};
  if (rel < 2400000) {  // scr: 16 threads/row, 8 cols each (pad >=100 with 0)
    const float* src; unsigned short* dst; int row, g;
    if (rel < 1600000) {
      row = rel >> 4; g = rel & 15;
      src = uscr + (size_t)row * 100;
      dst = ws + SCRU_OFF + (size_t)row * 128 + g * 8;
    } else {
      int q = rel - 1600000; row = q >> 4; g = q & 15;
      src = iscr + (size_t)row * 100;
      dst = ws + SCRI_OFF + (size_t)row * 128 + g * 8;
    }
    float4 va = (g < 13) ? *reinterpret_cast<const float4*>(src + g * 8) : z4;
    float4 vb = (g < 12) ? *reinterpret_cast<const float4*>(src + g * 8 + 4) : z4;
    st8(dst, va, vb);
    return;
  }
  rel -= 2400000;
  if (rel < 1200000) {  // emb: 8 threads/row, 8 cols each
    const float* src; unsigned short* dst; int row, g;
    if (rel < 800000) {
      row = rel >> 3; g = rel & 7;
      src = uemb + (size_t)row * 64;
      dst = ws + EMBU_OFF + (size_t)row * 64 + g * 8;
    } else {
      int q = rel - 800000; row = q >> 3; g = q & 7;
      src = iemb + (size_t)row * 64;
      dst = ws + EMBI_OFF + (size_t)row * 64 + g * 8;
    }
    float4 va = *reinterpret_cast<const float4*>(src + g * 8);
    float4 vb = *reinterpret_cast<const float4*>(src + g * 8 + 4);
    st8(dst, va, vb);
  }
}

// One MLP layer for wave w's 16-row band: Y = relu(A @ W^T + bias), stride 72.
template <int NT, int KT>
__device__ __forceinline__ void mlp_layer(const short8* a,
                                          const unsigned short* __restrict__ gw,
                                          const float* __restrict__ bias,
                                          unsigned short* __restrict__ Y,
                                          int w, int l15, int quad, int lane) {
#pragma unroll
  for (int n = 0; n < NT; ++n) {
    f32x4 acc = {0.f, 0.f, 0.f, 0.f};
#pragma unroll
    for (int k = 0; k < KT; ++k) {
      short8 bf = *reinterpret_cast<const short8*>(gw + ((n * KT + k) * 64 + lane) * 8);
      acc = __builtin_amdgcn_mfma_f32_16x16x32_bf16(a[k], bf, acc, 0, 0, 0);
    }
    const int col = n * 16 + l15;
    const float bv = bias[col];
#pragma unroll
    for (int r = 0; r < 4; ++r) {
      float v = fmaxf(acc[r] + bv, 0.f);
      Y[(w * 16 + quad * 4 + r) * 72 + col] = f2bf(v);
    }
  }
}

// pack two emb dwords (this lane: row r_half; partner: other row) into one
// Et dword covering cols (2*rbase, 2*rbase+1) of d-row (2c+half).
__device__ __forceinline__ void et_pack_store(unsigned short* S, int etb,
                                              unsigned int v, int c, int half,
                                              int rbase) {
  unsigned int pv = (unsigned int)__shfl_xor((int)v, 32, 64);
  unsigned int packed = (half == 0) ? ((v & 0xffffu) | (pv << 16))
                                    : ((pv >> 16) | (v & 0xffff0000u));
  *reinterpret_cast<unsigned int*>(&S[etb + (2 * c + half) * 136 + 2 * rbase]) = packed;
}

__launch_bounds__(448, 4)
__global__ void cnn_mfma6(
    const unsigned short* __restrict__ ws,
    const float* __restrict__ b1, const float* __restrict__ b2,
    const float* __restrict__ b3, const float* __restrict__ b4,
    const float* __restrict__ w5, const float* __restrict__ b5,
    const int* __restrict__ uidx_t, const int* __restrict__ iidx_t,
    const int* __restrict__ uidxs, const int* __restrict__ iidxs,
    float* __restrict__ out) {
  __shared__ __align__(16) unsigned short S[S_TOT];
  __shared__ int s_nb[2][256];  // [buf][0..127 user, 128..255 item]
  __shared__ float s_red[NBP][7];

  const int b0 = blockIdx.x * NBP;
  const int tid = threadIdx.x;
  const int w = tid >> 6, lane = tid & 63;
  const int l15 = lane & 15, quad = lane >> 4;
  const int c = lane & 31, half = lane >> 5;

  const char* scru = (const char*)(ws + SCRU_OFF);
  const char* scri = (const char*)(ws + SCRI_OFF);
  const char* embu = (const char*)(ws + EMBU_OFF);
  const char* embi = (const char*)(ws + EMBI_OFF);

  // ---- zero Et col-pads (j in [100,128)) of both buffers, once ----
  for (int q = tid; q < 1792; q += 448) {
    const int buf = q / 896, rem = q - buf * 896;
    const int row = rem / 14, cp = rem - row * 14;
    *reinterpret_cast<unsigned int*>(&S[buf * 8704 + row * 136 + 100 + cp * 2]) = 0u;
  }

  // ---- prologue: nb rows for b0 (to LDS) and b0+1 (to reg) ----
  int nbreg = 0;
  if (tid < 256) {
    const int col = tid & 127;
    const bool isu = tid < 128;
    const int* idx_t = isu ? uidx_t : iidx_t;
    int h0 = isu ? uidxs[b0] : iidxs[b0];
    s_nb[0][tid] = (col < KN) ? idx_t[(size_t)h0 * KN + col] : 0;
    int h1 = isu ? uidxs[b0 + 1] : iidxs[b0 + 1];
    nbreg = (col < KN) ? idx_t[(size_t)h1 * KN + col] : 0;
  }
  __syncthreads();

  // ---- prologue: gather + stage Et(b0,user) -> ETB0; load a_cur ----
  short8 a_cur[4];
  {
    const int m = s_nb[0][w * 16 + l15];
#pragma unroll
    for (int k = 0; k < 4; ++k)
      a_cur[k] = *reinterpret_cast<const short8*>(
          scru + ((size_t)(unsigned)m << 8) + k * 64 + quad * 16);
  }
#pragma unroll
  for (int rr = 0; rr < 8; ++rr) {
    const int rbase = w + rr * 7;
    if (rbase < 50) {
      const int r = rbase * 2 + half;
      unsigned int v = *reinterpret_cast<const unsigned int*>(
          embu + ((size_t)(unsigned)s_nb[0][r] << 7) + c * 4);
      et_pack_store(S, ETB0, v, c, half, rbase);
    }
  }
  __syncthreads();

#pragma unroll 1
  for (int b = 0; b < NBP; ++b) {
    const int cur = b & 1, nxt = cur ^ 1;

    // ================= phase A =================
    // issue gathers for (b, item)
    short8 a_nx[4];
    {
      const int m = s_nb[cur][128 + w * 16 + l15];
#pragma unroll
      for (int k = 0; k < 4; ++k)
        a_nx[k] = *reinterpret_cast<const short8*>(
            scri + ((size_t)(unsigned)m << 8) + k * 64 + quad * 16);
    }
    unsigned int etv[8];
#pragma unroll
    for (int rr = 0; rr < 8; ++rr) {
      const int rbase = w + rr * 7;
      if (rbase < 50) {
        const int r = rbase * 2 + half;
        etv[rr] = *reinterpret_cast<const unsigned int*>(
            embi + ((size_t)(unsigned)s_nb[cur][128 + r] << 7) + c * 4);
      }
    }
    // pool user from ETB0 -> Xu (wave-private band)
#pragma unroll
    for (int nt = 0; nt < 4; ++nt) {
      f32x4 acc = {0.f, 0.f, 0.f, 0.f};
#pragma unroll
      for (int kt = 0; kt < 4; ++kt) {
        short8 bf = *reinterpret_cast<const short8*>(
            S + ETB0 + (nt * 16 + l15) * 136 + kt * 32 + quad * 8);
        acc = __builtin_amdgcn_mfma_f32_16x16x32_bf16(a_cur[kt], bf, acc, 0, 0, 0);
      }
#pragma unroll
      for (int r = 0; r < 4; ++r)
        S[XU + (w * 16 + quad * 4 + r) * 72 + nt * 16 + l15] = f2bf(acc[r]);
    }
    // publish nb rows for batch b+1
    if (tid < 256 && b + 1 < NBP) s_nb[nxt][tid] = nbreg;
    // stage Et(b,item) -> ETB1
#pragma unroll
    for (int rr = 0; rr < 8; ++rr) {
      const int rbase = w + rr * 7;
      if (rbase < 50) et_pack_store(S, ETB1, etv[rr], c, half, rbase);
    }
#pragma unroll
    for (int k = 0; k < 4; ++k) a_cur[k] = a_nx[k];
    __syncthreads();  // alpha

    // ================= phase B =================
    // issue nb rows for b+2 (2-hop; lands during pool+MLP)
    if (tid < 256 && b + 2 < NBP) {
      const int col = tid & 127;
      const bool isu = tid < 128;
      const int* idx_t = isu ? uidx_t : iidx_t;
      int h = isu ? uidxs[b0 + b + 2] : iidxs[b0 + b + 2];
      nbreg = (col < KN) ? idx_t[(size_t)h * KN + col] : 0;
    }
    // issue gathers for (b+1, user)
    short8 a_nu[4];
    unsigned int etu[8];
    if (b + 1 < NBP) {
      const int m = s_nb[nxt][w * 16 + l15];
#pragma unroll
      for (int k = 0; k < 4; ++k)
        a_nu[k] = *reinterpret_cast<const short8*>(
            scru + ((size_t)(unsigned)m << 8) + k * 64 + quad * 16);
#pragma unroll
      for (int rr = 0; rr < 8; ++rr) {
        const int rbase = w + rr * 7;
        if (rbase < 50) {
          const int r = rbase * 2 + half;
          etu[rr] = *reinterpret_cast<const unsigned int*>(
              embu + ((size_t)(unsigned)s_nb[nxt][r] << 7) + c * 4);
        }
      }
    }
    // pool item from ETB1 -> Xi
#pragma unroll
    for (int nt = 0; nt < 4; ++nt) {
      f32x4 acc = {0.f, 0.f, 0.f, 0.f};
#pragma unroll
      for (int kt = 0; kt < 4; ++kt) {
        short8 bf = *reinterpret_cast<const short8*>(
            S + ETB1 + (nt * 16 + l15) * 136 + kt * 32 + quad * 8);
        acc = __builtin_amdgcn_mfma_f32_16x16x32_bf16(a_cur[kt], bf, acc, 0, 0, 0);
      }
#pragma unroll
      for (int r = 0; r < 4; ++r)
        S[XI + (w * 16 + quad * 4 + r) * 72 + nt * 16 + l15] = f2bf(acc[r]);
    }
    // stage Et(b+1,user) -> ETB0 (safe post-alpha) and retire etu regs early
    if (b + 1 < NBP) {
#pragma unroll
      for (int rr = 0; rr < 8; ++rr) {
        const int rbase = w + rr * 7;
        if (rbase < 50) et_pack_store(S, ETB0, etu[rr], c, half, rbase);
      }
#pragma unroll
      for (int k = 0; k < 4; ++k) a_cur[k] = a_nu[k];
    }

    // ---- MLP on wave-private bands ----
    const unsigned short* xu_row = S + XU + (w * 16 + l15) * 72;
    const unsigned short* xi_row = S + XI + (w * 16 + l15) * 72;
    {
      short8 a[4];
      a[0] = *reinterpret_cast<const short8*>(xu_row + quad * 8);
      a[1] = *reinterpret_cast<const short8*>(xu_row + 32 + quad * 8);
      a[2] = *reinterpret_cast<const short8*>(xi_row + quad * 8);
      a[3] = *reinterpret_cast<const short8*>(xi_row + 32 + quad * 8);
      mlp_layer<4, 4>(a, ws + W1_OFF, b1, S + XU, w, l15, quad, lane);
    }
    {
      short8 a[2];
      a[0] = *reinterpret_cast<const short8*>(xu_row + quad * 8);
      a[1] = *reinterpret_cast<const short8*>(xu_row + 32 + quad * 8);
      mlp_layer<4, 2>(a, ws + W2_OFF, b2, S + XI, w, l15, quad, lane);
    }
    {
      short8 a[2];
      a[0] = *reinterpret_cast<const short8*>(xi_row + quad * 8);
      a[1] = *reinterpret_cast<const short8*>(xi_row + 32 + quad * 8);
      mlp_layer<2, 2>(a, ws + W3_OFF, b3, S + XU, w, l15, quad, lane);
    }
    {  // L4 (32->32, relu) fused with L5 (32->1) + sigmoid + partial mean
      short8 a = *reinterpret_cast<const short8*>(xu_row + quad * 8);
      float dot[4] = {0.f, 0.f, 0.f, 0.f};
#pragma unroll
      for (int n = 0; n < 2; ++n) {
        f32x4 acc = {0.f, 0.f, 0.f, 0.f};
        short8 bf = *reinterpret_cast<const short8*>(ws + W4_OFF + (n * 64 + lane) * 8);
        acc = __builtin_amdgcn_mfma_f32_16x16x32_bf16(a, bf, acc, 0, 0, 0);
        const int col = n * 16 + l15;
        const float bv = b4[col], wv = w5[col];
#pragma unroll
        for (int r = 0; r < 4; ++r) {
          float v = fmaxf(acc[r] + bv, 0.f);
          dot[r] = fmaf(v, wv, dot[r]);
        }
      }
      float wsum = 0.f;
      const float bb5 = b5[0];
#pragma unroll
      for (int r = 0; r < 4; ++r) {
        float s = dot[r];
        s += __shfl_xor(s, 1, 64);
        s += __shfl_xor(s, 2, 64);
        s += __shfl_xor(s, 4, 64);
        s += __shfl_xor(s, 8, 64);
        const int row = w * 16 + quad * 4 + r;
        if (l15 == 0 && row < KN) wsum += 1.f / (1.f + expf(-(s + bb5)));
      }
      wsum += __shfl_xor(wsum, 16, 64);
      wsum += __shfl_xor(wsum, 32, 64);
      if (lane == 0) s_red[b][w] = wsum;
    }
    __syncthreads();  // beta
  }

  // ---- outputs (all s_red published by last beta) ----
  if (tid < NBP) {
    float t = 0.f;
#pragma unroll
    for (int i = 0; i < 7; ++i) t += s_red[tid][i];
    out[b0 + tid] = t * (1.0f / KN);
  }
}

extern "C" void kernel_launch(void* const* d_in, const int* in_sizes, int n_in,
                              void* d_out, int out_size, void* d_ws,
                              size_t ws_size, hipStream_t stream) {
  const float* user_emb = (const float*)d_in[0];
  const float* item_emb = (const float*)d_in[1];
  const float* user_scr = (const float*)d_in[2];
  const float* item_scr = (const float*)d_in[3];
  const float* w1 = (const float*)d_in[4];
  const float* b1 = (const float*)d_in[5];
  const float* w2 = (const float*)d_in[6];
  const float* b2 = (const float*)d_in[7];
  const float* w3 = (const float*)d_in[8];
  const float* b3 = (const float*)d_in[9];
  const float* w4 = (const float*)d_in[10];
  const float* b4 = (const float*)d_in[11];
  const float* w5 = (const float*)d_in[12];
  const float* b5 = (const float*)d_in[13];
  const int* user_idx_t = (const int*)d_in[14];
  const int* item_idx_t = (const int*)d_in[15];
  const int* user_idxs = (const int*)d_in[16];
  const int* item_idxs = (const int*)d_in[17];
  unsigned short* wsw = (unsigned short*)d_ws;

  prep<<<dim3((15360 + 2400000 + 1200000 + 255) / 256), dim3(256), 0, stream>>>(
      w1, w2, w3, w4, user_scr, item_scr, user_emb, item_emb, wsw);

  const int B = in_sizes[16];  // 8192
  cnn_mfma6<<<dim3(B / NBP), dim3(448), 0, stream>>>(
      wsw, b1, b2, b3, b4, w5, b5, user_idx_t, item_idx_t, user_idxs,
      item_idxs, (float*)d_out);
}